// Round 3
// baseline (99.277 us; speedup 1.0000x reference)
//
#include <hip/hip_runtime.h>
#include <hip/hip_bf16.h>

#define SEQ 128
#define DM 32

// log2(e) * 2^23 : natural-exponent slope -> float-exponent-bit units
#define K_LOG2E_2P23 12102203.161561485f
// Schraudolph bias: (127 - 0.04384) * 2^23, minimax-balanced relative error (+/- ~3%)
#define SCHRAUDOLPH_C 1064985472.0f
#define INV_SQRT_D 0.17677669529663687f  // 1/sqrt(32)

// ---------------------------------------------------------------------------
// Fused kernel. Algebra (see R0): tokens are affine in the scalar x[b,s], so
// the whole attention collapses to
//   out[b] = alpha * mean_q( m(t_q) ) + beta,
//   m(t)   = sum_k x_k e^{t x_k} / sum_k e^{t x_k},   t_q = a*x_q + c
// with 4 scalars (a,c,alpha,beta) folded from the weights. K-bias cancels in
// softmax. exp via Schraudolph bit-trick: e = bitcast(int(T*x + M)) with T,M
// pre-scaled into float-exponent-bit units; constant relative error cancels
// in the softmax ratio.
//
// One wave per 2 rows; no inter-wave communication -> no __syncthreads.
// Each wave folds the weight constants itself (~300 cyc, L1-hot, amortized
// over 2 rows of 2048-cyc work). LDS used only for same-wave row broadcast.
// ---------------------------------------------------------------------------

template <bool CLAMP>
__device__ __forceinline__ void row_loop(const float4* __restrict__ row4,
                                         float T0, float M0, float T1, float M1,
                                         float& s0, float& sxw0,
                                         float& s1, float& sxw1) {
#pragma unroll
    for (int k4 = 0; k4 < SEQ / 4; ++k4) {
        const float4 xv = row4[k4];  // ds_read_b128, all-lane broadcast
#pragma unroll
        for (int j = 0; j < 4; ++j) {
            const float xk = (j == 0) ? xv.x : (j == 1) ? xv.y : (j == 2) ? xv.z : xv.w;
            float v0 = fmaf(T0, xk, M0);
            float v1 = fmaf(T1, xk, M1);
            if (CLAMP) {
                v0 = fmaxf(v0, 0.0f);
                v1 = fmaxf(v1, 0.0f);
            }
            const float e0 = __int_as_float((int)v0);
            const float e1 = __int_as_float((int)v1);
            s0 += e0; sxw0 = fmaf(e0, xk, sxw0);
            s1 += e1; sxw1 = fmaf(e1, xk, sxw1);
        }
    }
}

#define WAVES_PER_BLOCK 4
#define ROWS_PER_WAVE 2

__global__ __launch_bounds__(256) void attn_fused_kernel(
        const float* __restrict__ x,
        const float* __restrict__ Wt, const float* __restrict__ bt,
        const float* __restrict__ Wq, const float* __restrict__ bq,
        const float* __restrict__ Wk,
        const float* __restrict__ Wv, const float* __restrict__ bv,
        const float* __restrict__ Wo, const float* __restrict__ bo,
        float* __restrict__ out, int B) {
    __shared__ float sx[WAVES_PER_BLOCK][ROWS_PER_WAVE][SEQ];

    const int wave = threadIdx.x >> 6;
    const int lane = threadIdx.x & 63;
    const int wg = blockIdx.x * WAVES_PER_BLOCK + wave;
    int b0 = wg * ROWS_PER_WAVE;
    int b1 = b0 + 1;
    if (b0 >= B) b0 = B - 1;   // tail dup; idempotent writes
    if (b1 >= B) b1 = B - 1;

    // ---- issue both rows' x loads first (latency hidden under const fold) ----
    const float* xr0 = x + (size_t)b0 * SEQ;
    const float* xr1 = x + (size_t)b1 * SEQ;
    const float x00 = xr0[lane];
    const float x01 = xr0[lane + 64];
    const float x10 = xr1[lane];
    const float x11 = xr1[lane + 64];

    // ---- fold weights to 4 scalars (all 64 lanes: e = lane&31, d-half) ----
    const int e  = lane & 31;
    const int dh = lane >> 5;  // 0 or 1
    float qw = 0.f, qb = 0.f, kw = 0.f, vw = 0.f, vb = 0.f;
#pragma unroll
    for (int i = 0; i < 16; ++i) {
        const int d = dh * 16 + i;
        const float wt  = Wt[d];
        const float bb  = bt[d];
        const float wqe = Wq[d * DM + e];
        const float wke = Wk[d * DM + e];
        const float wve = Wv[d * DM + e];
        qw = fmaf(wt, wqe, qw); qb = fmaf(bb, wqe, qb);
        kw = fmaf(wt, wke, kw);
        vw = fmaf(wt, wve, vw); vb = fmaf(bb, wve, vb);
    }
    // combine the two d-halves (each e now present in 2 lanes, identical)
    qw += __shfl_xor(qw, 32); qb += __shfl_xor(qb, 32);
    kw += __shfl_xor(kw, 32);
    vw += __shfl_xor(vw, 32); vb += __shfl_xor(vb, 32);
    qb += bq[e];
    vb += bv[e];
    const float wo = Wo[e];
    float pa  = qw * kw;   // -> 2*a*sqrt(D) after 64-lane sum
    float pc  = qb * kw;
    float pal = vw * wo;
    float pbe = vb * wo;
#pragma unroll
    for (int off = 32; off > 0; off >>= 1) {
        pa  += __shfl_xor(pa,  off);
        pc  += __shfl_xor(pc,  off);
        pal += __shfl_xor(pal, off);
        pbe += __shfl_xor(pbe, off);
    }
    // 64-lane sum double-counts each e -> *0.5
    const float A     = pa * (0.5f * INV_SQRT_D * K_LOG2E_2P23);
    const float C     = pc * (0.5f * INV_SQRT_D * K_LOG2E_2P23);
    const float alpha = pal * 0.5f;
    const float beta  = fmaf(pbe, 0.5f, bo[0]);
    const float absA = fabsf(A), absC = fabsf(C);

    // ---- per-row processing (no cross-wave LDS sharing -> no barrier) ----
#pragma unroll
    for (int r = 0; r < ROWS_PER_WAVE; ++r) {
        const float x0 = r ? x10 : x00;
        const float x1 = r ? x11 : x01;
        const int b    = r ? b1 : b0;

        sx[wave][r][lane]      = x0;
        sx[wave][r][lane + 64] = x1;

        float mx = fmaxf(x0, x1);
        float mn = fminf(x0, x1);
#pragma unroll
        for (int off = 32; off > 0; off >>= 1) {
            mx = fmaxf(mx, __shfl_xor(mx, off));
            mn = fminf(mn, __shfl_xor(mn, off));
        }

        const float T0 = fmaf(A, x0, C);
        const float T1 = fmaf(A, x1, C);
        const float m0 = fmaxf(T0 * mx, T0 * mn);  // exact max_k of T*x_k
        const float m1 = fmaxf(T1 * mx, T1 * mn);
        const float M0 = SCHRAUDOLPH_C - m0;
        const float M1 = SCHRAUDOLPH_C - m1;

        float s0 = 0.f, sxw0 = 0.f, s1 = 0.f, sxw1 = 0.f;
        const float4* row4 = (const float4*)sx[wave][r];

        // wave-uniform overflow-risk check (clamp-free fast path)
        const float maxabs = fmaxf(fabsf(mx), fabsf(mn));
        const float tmax = fmaf(absA, maxabs, absC);
        if (tmax * (mx - mn) < 1.0e9f) {
            row_loop<false>(row4, T0, M0, T1, M1, s0, sxw0, s1, sxw1);
        } else {
            row_loop<true>(row4, T0, M0, T1, M1, s0, sxw0, s1, sxw1);
        }

        float msum = sxw0 * __builtin_amdgcn_rcpf(s0) +
                     sxw1 * __builtin_amdgcn_rcpf(s1);
#pragma unroll
        for (int off = 32; off > 0; off >>= 1)
            msum += __shfl_xor(msum, off);

        if (lane == 0)
            out[b] = fmaf(alpha, msum * (1.0f / 128.0f), beta);
    }
}

extern "C" void kernel_launch(void* const* d_in, const int* in_sizes, int n_in,
                              void* d_out, int out_size, void* d_ws, size_t ws_size,
                              hipStream_t stream) {
    const float* x  = (const float*)d_in[0];
    const float* Wt = (const float*)d_in[1];
    const float* bt = (const float*)d_in[2];
    const float* Wq = (const float*)d_in[3];
    const float* bq = (const float*)d_in[4];
    const float* Wk = (const float*)d_in[5];
    // bk (d_in[6]) provably cancels in softmax -> unused
    const float* Wv = (const float*)d_in[7];
    const float* bv = (const float*)d_in[8];
    const float* Wo = (const float*)d_in[9];
    const float* bo = (const float*)d_in[10];
    float* out = (float*)d_out;

    const int B = in_sizes[0] / SEQ;

    const int rows_per_block = WAVES_PER_BLOCK * ROWS_PER_WAVE;
    const int grid = (B + rows_per_block - 1) / rows_per_block;
    attn_fused_kernel<<<grid, 256, 0, stream>>>(x, Wt, bt, Wq, bq, Wk,
                                                Wv, bv, Wo, bo, out, B);
}

// Round 4
// 98.494 us; speedup vs baseline: 1.0080x; 1.0080x over previous
//
#include <hip/hip_runtime.h>
#include <hip/hip_bf16.h>

#define SEQ 128
#define DM 32

// log2(e) * 2^23 : natural-exponent slope -> float-exponent-bit units
#define K_LOG2E_2P23 12102203.161561485f
// Schraudolph bias: (127 - 0.04384) * 2^23, minimax-balanced rel error (+/- ~3%)
#define SCHRAUDOLPH_C 1064985472.0f
#define INV_SQRT_D 0.17677669529663687f  // 1/sqrt(32)

// ---------------------------------------------------------------------------
// Kernel 0 (1 block, 64 thr): fold weights to 4 scalars. Algebra (R0):
// tokens are affine in the scalar x[b,s] -> whole attention collapses to
//   out[b] = alpha * mean_q m(t_q) + beta,
//   m(t) = sum_k x_k e^{t x_k} / sum_k e^{t x_k},  t_q = a*x_q + c.
// K-bias cancels in softmax. A,C stored pre-scaled into exponent-bit units.
// ---------------------------------------------------------------------------
__global__ void precompute_consts(const float* __restrict__ Wt,
                                  const float* __restrict__ bt,
                                  const float* __restrict__ Wq,
                                  const float* __restrict__ bq,
                                  const float* __restrict__ Wk,
                                  const float* __restrict__ bk,
                                  const float* __restrict__ Wv,
                                  const float* __restrict__ bv,
                                  const float* __restrict__ Wo,
                                  const float* __restrict__ bo,
                                  float* __restrict__ consts) {
    int e = threadIdx.x;  // 0..63
    float qw = 0.f, qb = 0.f, kw = 0.f, vw = 0.f, vb = 0.f;
    float wo = 0.f;
    if (e < DM) {
        for (int d = 0; d < DM; ++d) {
            float wt = Wt[d];
            float bb = bt[d];
            qw = fmaf(wt, Wq[d * DM + e], qw);
            qb = fmaf(bb, Wq[d * DM + e], qb);
            kw = fmaf(wt, Wk[d * DM + e], kw);
            vw = fmaf(wt, Wv[d * DM + e], vw);
            vb = fmaf(bb, Wv[d * DM + e], vb);
        }
        qb += bq[e];
        vb += bv[e];
        wo = Wo[e];  // Wo is (32,1) -> flat index e
    }
    float pa  = qw * kw;   // -> a * sqrt(D)
    float pc  = qb * kw;   // -> c * sqrt(D)
    float pal = vw * wo;   // -> alpha
    float pbe = vb * wo;   // -> beta - bo
    for (int off = 32; off > 0; off >>= 1) {
        pa  += __shfl_down(pa, off);
        pc  += __shfl_down(pc, off);
        pal += __shfl_down(pal, off);
        pbe += __shfl_down(pbe, off);
    }
    if (e == 0) {
        consts[0] = pa * (INV_SQRT_D * K_LOG2E_2P23);  // A (exp-bit units)
        consts[1] = pc * (INV_SQRT_D * K_LOG2E_2P23);  // C (exp-bit units)
        consts[2] = pal;                               // alpha
        consts[3] = pbe + bo[0];                       // beta
    }
}

// ---------------------------------------------------------------------------
// Inner loop: Schraudolph fast-exp softmax weighted mean, row broadcast via
// SGPRs. xr is wave-uniform -> xs[] loads compile to s_load_dwordx* on the
// SMEM pipe (zero LDS traffic; xk is an SGPR operand to the VALU fmas).
// 8 VALU ops per (k, 2 q's) = 4 per pair. CLAMP guards int-underflow in the
// rare high-dynamic-range row (wave-uniform scalar branch).
// ---------------------------------------------------------------------------
template <bool CLAMP>
__device__ __forceinline__ void row_loop_sgpr(const float* __restrict__ xr,
                                              float T0, float M0,
                                              float T1, float M1,
                                              float& s0, float& sxw0,
                                              float& s1, float& sxw1) {
#pragma unroll
    for (int c = 0; c < SEQ / 16; ++c) {
        float xs[16];
#pragma unroll
        for (int i = 0; i < 16; ++i) xs[i] = xr[c * 16 + i];  // uniform -> s_load
#pragma unroll
        for (int i = 0; i < 16; ++i) {
            const float xk = xs[i];
            float v0 = fmaf(T0, xk, M0);
            float v1 = fmaf(T1, xk, M1);
            if (CLAMP) {
                v0 = fmaxf(v0, 0.0f);
                v1 = fmaxf(v1, 0.0f);
            }
            const float e0 = __int_as_float((int)v0);
            const float e1 = __int_as_float((int)v1);
            s0 += e0; sxw0 = fmaf(e0, xk, sxw0);
            s1 += e1; sxw1 = fmaf(e1, xk, sxw1);
        }
    }
}

#define WAVES_PER_BLOCK 4

__global__ __launch_bounds__(256) void attn_rowmean_kernel(
        const float* __restrict__ x,
        const float* __restrict__ consts,
        float* __restrict__ out, int B) {
    const int lane = threadIdx.x & 63;
    // Force wave id into an SGPR so b / xr are provably wave-uniform.
    const int wave = __builtin_amdgcn_readfirstlane(threadIdx.x >> 6);
    int b = blockIdx.x * WAVES_PER_BLOCK + wave;
    if (b >= B) b = B - 1;  // tail dup; idempotent writes

    const float A     = consts[0];
    const float C     = consts[1];
    const float alpha = consts[2];
    const float beta  = consts[3];

    const float* xr = x + (size_t)b * SEQ;  // wave-uniform
    const float x0 = xr[lane];              // divergent loads just for minmax
    const float x1 = xr[lane + 64];

    // row max/min via wave butterfly
    float mx = fmaxf(x0, x1);
    float mn = fminf(x0, x1);
#pragma unroll
    for (int off = 32; off > 0; off >>= 1) {
        mx = fmaxf(mx, __shfl_xor(mx, off));
        mn = fminf(mn, __shfl_xor(mn, off));
    }

    // T_q in exponent-bit units; M_q = bias - max_k(T_q x_k) (exact via mx/mn)
    const float T0 = fmaf(A, x0, C);
    const float T1 = fmaf(A, x1, C);
    const float m0 = fmaxf(T0 * mx, T0 * mn);
    const float m1 = fmaxf(T1 * mx, T1 * mn);
    const float M0 = SCHRAUDOLPH_C - m0;
    const float M1 = SCHRAUDOLPH_C - m1;

    float s0 = 0.f, sxw0 = 0.f, s1 = 0.f, sxw1 = 0.f;

    // Wave-uniform overflow-risk check -> scalar branch (readfirstlane).
    const float maxabs = fmaxf(fabsf(mx), fabsf(mn));
    const float tmax = fmaf(fabsf(A), maxabs, fabsf(C));
    const int fast = (tmax * (mx - mn) < 1.0e9f) ? 1 : 0;
    if (__builtin_amdgcn_readfirstlane(fast)) {
        row_loop_sgpr<false>(xr, T0, M0, T1, M1, s0, sxw0, s1, sxw1);
    } else {
        row_loop_sgpr<true>(xr, T0, M0, T1, M1, s0, sxw0, s1, sxw1);
    }

    // m_q for this lane's two q's, then mean over the row's 128 q.
    float msum = sxw0 * __builtin_amdgcn_rcpf(s0) +
                 sxw1 * __builtin_amdgcn_rcpf(s1);
#pragma unroll
    for (int off = 32; off > 0; off >>= 1)
        msum += __shfl_xor(msum, off);

    if (lane == 0)
        out[b] = fmaf(alpha, msum * (1.0f / 128.0f), beta);
}

extern "C" void kernel_launch(void* const* d_in, const int* in_sizes, int n_in,
                              void* d_out, int out_size, void* d_ws, size_t ws_size,
                              hipStream_t stream) {
    const float* x  = (const float*)d_in[0];
    const float* Wt = (const float*)d_in[1];
    const float* bt = (const float*)d_in[2];
    const float* Wq = (const float*)d_in[3];
    const float* bq = (const float*)d_in[4];
    const float* Wk = (const float*)d_in[5];
    const float* bk = (const float*)d_in[6];  // cancels in softmax; unused
    const float* Wv = (const float*)d_in[7];
    const float* bv = (const float*)d_in[8];
    const float* Wo = (const float*)d_in[9];
    const float* bo = (const float*)d_in[10];
    float* out = (float*)d_out;
    float* consts = (float*)d_ws;  // 4 floats

    const int B = in_sizes[0] / SEQ;

    precompute_consts<<<1, 64, 0, stream>>>(Wt, bt, Wq, bq, Wk, bk, Wv, bv,
                                            Wo, bo, consts);

    const int grid = (B + WAVES_PER_BLOCK - 1) / WAVES_PER_BLOCK;
    attn_rowmean_kernel<<<grid, 256, 0, stream>>>(x, consts, out, B);
}

// Round 5
// 98.072 us; speedup vs baseline: 1.0123x; 1.0043x over previous
//
#include <hip/hip_runtime.h>
#include <hip/hip_bf16.h>

#define SEQ 128
#define DM 32

// log2(e) * 2^23 : natural-exponent slope -> float-exponent-bit units
#define K_LOG2E_2P23 12102203.161561485f
// Schraudolph bias: (127 - 0.04384) * 2^23, minimax-balanced rel error (+/- ~3%)
#define SCHRAUDOLPH_C 1064985472.0f
#define INV_SQRT_D 0.17677669529663687f  // 1/sqrt(32)

// ---------------------------------------------------------------------------
// Single fused kernel. Algebra (R0): tokens are affine in the scalar x[b,s],
// so the whole attention collapses to
//   out[b] = alpha * mean_q m(t_q) + beta,
//   m(t)   = sum_k x_k e^{t x_k} / sum_k e^{t x_k},  t_q = a*x_q + c
// with 4 scalars folded from the weights (K-bias cancels in softmax).
// exp via Schraudolph bit-trick in float-exponent-bit units; the constant
// component of its +/-3% relative error cancels in the softmax ratio.
//
// Launch structure (R3 post-mortem): the weight fold must NOT run per wave.
// 1024-thread blocks; wave 0 folds weights -> LDS while the other 15 waves
// stage their x rows + min/max; one __syncthreads; then 16 independent
// R2-proven row loops (one row per wave, LDS float4 broadcast).
// __launch_bounds__(1024,8): 2 blocks/CU = 32 waves/CU, same TLP as R2, and
// the partner block's waves issue during this block's fold barrier.
// ---------------------------------------------------------------------------

template <bool CLAMP>
__device__ __forceinline__ void row_loop(const float4* __restrict__ row4,
                                         float T0, float M0, float T1, float M1,
                                         float& s0, float& sxw0,
                                         float& s1, float& sxw1) {
#pragma unroll
    for (int k4 = 0; k4 < SEQ / 4; ++k4) {
        const float4 xv = row4[k4];  // ds_read_b128, all-lane broadcast
#pragma unroll
        for (int j = 0; j < 4; ++j) {
            const float xk = (j == 0) ? xv.x : (j == 1) ? xv.y : (j == 2) ? xv.z : xv.w;
            float v0 = fmaf(T0, xk, M0);
            float v1 = fmaf(T1, xk, M1);
            if (CLAMP) {
                v0 = fmaxf(v0, 0.0f);
                v1 = fmaxf(v1, 0.0f);
            }
            const float e0 = __int_as_float((int)v0);
            const float e1 = __int_as_float((int)v1);
            s0 += e0; sxw0 = fmaf(e0, xk, sxw0);
            s1 += e1; sxw1 = fmaf(e1, xk, sxw1);
        }
    }
}

#define WAVES_PER_BLOCK 16  // 1024 threads

__global__ __launch_bounds__(1024, 8) void attn_fused_kernel(
        const float* __restrict__ x,
        const float* __restrict__ Wt, const float* __restrict__ bt,
        const float* __restrict__ Wq, const float* __restrict__ bq,
        const float* __restrict__ Wk,
        const float* __restrict__ Wv, const float* __restrict__ bv,
        const float* __restrict__ Wo, const float* __restrict__ bo,
        float* __restrict__ out, int B) {
    __shared__ float sx[WAVES_PER_BLOCK][SEQ];
    __shared__ float sconsts[4];

    const int wave = threadIdx.x >> 6;
    const int lane = threadIdx.x & 63;
    int b = blockIdx.x * WAVES_PER_BLOCK + wave;
    if (b >= B) b = B - 1;  // tail dup; idempotent writes

    // ---- every wave: stage its row + min/max (overlaps wave 0's fold) ----
    const float* xr = x + (size_t)b * SEQ;
    const float x0 = xr[lane];
    const float x1 = xr[lane + 64];
    sx[wave][lane]      = x0;
    sx[wave][lane + 64] = x1;

    float mx = fmaxf(x0, x1);
    float mn = fminf(x0, x1);
#pragma unroll
    for (int off = 32; off > 0; off >>= 1) {
        mx = fmaxf(mx, __shfl_xor(mx, off));
        mn = fminf(mn, __shfl_xor(mn, off));
    }

    // ---- wave 0 only: fold weights to 4 scalars (64 lanes: e=lane&31) ----
    if (wave == 0) {
        const int e  = lane & 31;
        const int dh = lane >> 5;  // 0 or 1
        float qw = 0.f, qb = 0.f, kw = 0.f, vw = 0.f, vb = 0.f;
#pragma unroll
        for (int i = 0; i < 16; ++i) {
            const int d = dh * 16 + i;
            const float wt  = Wt[d];
            const float bb  = bt[d];
            const float wqe = Wq[d * DM + e];
            const float wke = Wk[d * DM + e];
            const float wve = Wv[d * DM + e];
            qw = fmaf(wt, wqe, qw); qb = fmaf(bb, wqe, qb);
            kw = fmaf(wt, wke, kw);
            vw = fmaf(wt, wve, vw); vb = fmaf(bb, wve, vb);
        }
        // combine the two d-halves (each e present in 2 lanes, identical after)
        qw += __shfl_xor(qw, 32); qb += __shfl_xor(qb, 32);
        kw += __shfl_xor(kw, 32);
        vw += __shfl_xor(vw, 32); vb += __shfl_xor(vb, 32);
        qb += bq[e];
        vb += bv[e];
        const float wo = Wo[e];
        float pa  = qw * kw;
        float pc  = qb * kw;
        float pal = vw * wo;
        float pbe = vb * wo;
#pragma unroll
        for (int off = 32; off > 0; off >>= 1) {
            pa  += __shfl_xor(pa,  off);
            pc  += __shfl_xor(pc,  off);
            pal += __shfl_xor(pal, off);
            pbe += __shfl_xor(pbe, off);
        }
        // 64-lane sum double-counts each e -> *0.5
        if (lane == 0) {
            sconsts[0] = pa * (0.5f * INV_SQRT_D * K_LOG2E_2P23);  // A
            sconsts[1] = pc * (0.5f * INV_SQRT_D * K_LOG2E_2P23);  // C
            sconsts[2] = pal * 0.5f;                               // alpha
            sconsts[3] = fmaf(pbe, 0.5f, bo[0]);                   // beta
        }
    }

    __syncthreads();

    const float A     = sconsts[0];
    const float C     = sconsts[1];
    const float alpha = sconsts[2];
    const float beta  = sconsts[3];

    // T_q in exponent-bit units; M_q = bias - max_k(T_q x_k) (exact via mx/mn)
    const float T0 = fmaf(A, x0, C);
    const float T1 = fmaf(A, x1, C);
    const float m0 = fmaxf(T0 * mx, T0 * mn);
    const float m1 = fmaxf(T1 * mx, T1 * mn);
    const float M0 = SCHRAUDOLPH_C - m0;
    const float M1 = SCHRAUDOLPH_C - m1;

    float s0 = 0.f, sxw0 = 0.f, s1 = 0.f, sxw1 = 0.f;
    const float4* row4 = (const float4*)sx[wave];

    // wave-uniform overflow-risk check (clamp-free fast path)
    const float maxabs = fmaxf(fabsf(mx), fabsf(mn));
    const float tmax = fmaf(fabsf(A), maxabs, fabsf(C));
    if (tmax * (mx - mn) < 1.0e9f) {
        row_loop<false>(row4, T0, M0, T1, M1, s0, sxw0, s1, sxw1);
    } else {
        row_loop<true>(row4, T0, M0, T1, M1, s0, sxw0, s1, sxw1);
    }

    // m_q for this lane's two q's, then mean over the row's 128 q.
    float msum = sxw0 * __builtin_amdgcn_rcpf(s0) +
                 sxw1 * __builtin_amdgcn_rcpf(s1);
#pragma unroll
    for (int off = 32; off > 0; off >>= 1)
        msum += __shfl_xor(msum, off);

    if (lane == 0)
        out[b] = fmaf(alpha, msum * (1.0f / 128.0f), beta);
}

extern "C" void kernel_launch(void* const* d_in, const int* in_sizes, int n_in,
                              void* d_out, int out_size, void* d_ws, size_t ws_size,
                              hipStream_t stream) {
    const float* x  = (const float*)d_in[0];
    const float* Wt = (const float*)d_in[1];
    const float* bt = (const float*)d_in[2];
    const float* Wq = (const float*)d_in[3];
    const float* bq = (const float*)d_in[4];
    const float* Wk = (const float*)d_in[5];
    // bk (d_in[6]) provably cancels in softmax -> unused
    const float* Wv = (const float*)d_in[7];
    const float* bv = (const float*)d_in[8];
    const float* Wo = (const float*)d_in[9];
    const float* bo = (const float*)d_in[10];
    float* out = (float*)d_out;

    const int B = in_sizes[0] / SEQ;

    const int grid = (B + WAVES_PER_BLOCK - 1) / WAVES_PER_BLOCK;
    attn_fused_kernel<<<grid, 1024, 0, stream>>>(x, Wt, bt, Wq, bq, Wk,
                                                 Wv, bv, Wo, bo, out, B);
}

// Round 6
// 89.371 us; speedup vs baseline: 1.1108x; 1.0973x over previous
//
#include <hip/hip_runtime.h>

#define SEQ 128
#define DM 32

// log2(e) * 2^23 : natural-exponent slope -> float-exponent-bit units
#define K_LOG2E_2P23 12102203.161561485f
// Schraudolph bias: (127 - 0.04384) * 2^23, minimax-balanced rel error (+/- ~3%)
#define SCHRAUDOLPH_C 1064985472.0f
#define INV_SQRT_D 0.17677669529663687f  // 1/sqrt(32)

// ---------------------------------------------------------------------------
// Kernel 0 (1 block, 64 thr): fold weights to 4 scalars. Algebra (R0):
// tokens are affine in the scalar x[b,s] -> the whole attention collapses to
//   out[b] = alpha * mean_q m(t_q) + beta,
//   m(t) = sum_k x_k e^{t x_k} / sum_k e^{t x_k},  t_q = a*x_q + c.
// K-bias cancels in softmax. A,C stored pre-scaled into exp-bit units.
// ---------------------------------------------------------------------------
__global__ void precompute_consts(const float* __restrict__ Wt,
                                  const float* __restrict__ bt,
                                  const float* __restrict__ Wq,
                                  const float* __restrict__ bq,
                                  const float* __restrict__ Wk,
                                  const float* __restrict__ bk,
                                  const float* __restrict__ Wv,
                                  const float* __restrict__ bv,
                                  const float* __restrict__ Wo,
                                  const float* __restrict__ bo,
                                  float* __restrict__ consts) {
    int e = threadIdx.x;  // 0..63
    float qw = 0.f, qb = 0.f, kw = 0.f, vw = 0.f, vb = 0.f;
    float wo = 0.f;
    if (e < DM) {
        for (int d = 0; d < DM; ++d) {
            float wt = Wt[d];
            float bb = bt[d];
            qw = fmaf(wt, Wq[d * DM + e], qw);
            qb = fmaf(bb, Wq[d * DM + e], qb);
            kw = fmaf(wt, Wk[d * DM + e], kw);
            vw = fmaf(wt, Wv[d * DM + e], vw);
            vb = fmaf(bb, Wv[d * DM + e], vb);
        }
        qb += bq[e];
        vb += bv[e];
        wo = Wo[e];  // Wo is (32,1) -> flat index e
    }
    float pa  = qw * kw;   // -> a * sqrt(D)
    float pc  = qb * kw;   // -> c * sqrt(D)
    float pal = vw * wo;   // -> alpha
    float pbe = vb * wo;   // -> beta - bo
    for (int off = 32; off > 0; off >>= 1) {
        pa  += __shfl_down(pa, off);
        pc  += __shfl_down(pc, off);
        pal += __shfl_down(pal, off);
        pbe += __shfl_down(pbe, off);
    }
    if (e == 0) {
        consts[0] = pa * (INV_SQRT_D * K_LOG2E_2P23);  // A (exp-bit units)
        consts[1] = pc * (INV_SQRT_D * K_LOG2E_2P23);  // C (exp-bit units)
        consts[2] = pal;                               // alpha
        consts[3] = pbe + bo[0];                       // beta
    }
}

// ---------------------------------------------------------------------------
// Table-point series: S = sum_k e_k, U = sum_k e_k x_k at this lane's t-point.
// Schraudolph fast-exp: e = bitcast(int(Tp*x + Mp)), Mp = bias - max_k(Tp x).
// CLAMP variant guards int-underflow for high-dynamic-range rows.
// ---------------------------------------------------------------------------
template <bool CLAMP>
__device__ __forceinline__ void table_loop(const float4* __restrict__ row4,
                                           float Tp, float Mp,
                                           float& S, float& U) {
#pragma unroll
    for (int k4 = 0; k4 < SEQ / 4; ++k4) {
        const float4 xv = row4[k4];  // ds_read_b128, all-lane broadcast
#pragma unroll
        for (int j = 0; j < 4; ++j) {
            const float xk = (j == 0) ? xv.x : (j == 1) ? xv.y : (j == 2) ? xv.z : xv.w;
            float v = fmaf(Tp, xk, Mp);
            if (CLAMP) v = fmaxf(v, 0.0f);
            const float e = __int_as_float((int)v);
            S += e;
            U = fmaf(e, xk, U);
        }
    }
}

// ---------------------------------------------------------------------------
// Main kernel: one wave per row. All 128 q share the scalar function m(t);
// build a 64-point table (one point per lane: p=lane, T_p = Tlo+(p-1)h with
// ghost points p=0,63 evaluated exactly), then Catmull-Rom cubic interpolate
// each q's m(t_q) from LDS. Halves the dominant per-row exp workload
// (1 series/lane instead of 2 q-series/lane).
// ---------------------------------------------------------------------------
#define WAVES_PER_BLOCK 4
#define NPTS 64

__global__ __launch_bounds__(256) void attn_rowmean_kernel(
        const float* __restrict__ x,
        const float* __restrict__ consts,
        float* __restrict__ out, int B) {
    __shared__ float sx[WAVES_PER_BLOCK][SEQ];
    __shared__ float tab[WAVES_PER_BLOCK][NPTS];

    const int wave = threadIdx.x >> 6;
    const int lane = threadIdx.x & 63;
    int b = blockIdx.x * WAVES_PER_BLOCK + wave;
    if (b >= B) b = B - 1;  // tail dup; idempotent writes

    const float A     = consts[0];
    const float C     = consts[1];
    const float alpha = consts[2];
    const float beta  = consts[3];

    const float* xr = x + (size_t)b * SEQ;
    const float x0 = xr[lane];
    const float x1 = xr[lane + 64];
    sx[wave][lane]      = x0;
    sx[wave][lane + 64] = x1;

    // row max/min via wave butterfly
    float mx = fmaxf(x0, x1);
    float mn = fminf(x0, x1);
#pragma unroll
    for (int off = 32; off > 0; off >>= 1) {
        mx = fmaxf(mx, __shfl_xor(mx, off));
        mn = fminf(mn, __shfl_xor(mn, off));
    }

    // t-range over this row's q values (exp-bit units)
    const float Ta = fmaf(A, mn, C);
    const float Tb = fmaf(A, mx, C);
    const float Tlo = fminf(Ta, Tb);
    const float Thi = fmaxf(Ta, Tb);
    const float spanT = Thi - Tlo;
    const float h = spanT * (1.0f / 61.0f);
    const float invh = (spanT > 1e-6f) ? (61.0f / spanT) : 0.0f;

    // this lane's table point: p=lane, T_p = Tlo + (p-1)*h  (p=0,63 = ghosts)
    const float Tp = fmaf((float)(lane - 1), h, Tlo);
    const float Mp = SCHRAUDOLPH_C - fmaxf(Tp * mx, Tp * mn);

    float S = 0.f, U = 0.f;
    const float4* row4 = (const float4*)sx[wave];

    // wave-uniform overflow-risk check over the extreme table points
    const float maxTpt = fmaxf(fabsf(Tlo - h), fabsf(Thi + h));
    if (maxTpt * (mx - mn) < 1.0e9f) {
        table_loop<false>(row4, Tp, Mp, S, U);
    } else {
        table_loop<true>(row4, Tp, Mp, S, U);
    }

    tab[wave][lane] = U * __builtin_amdgcn_rcpf(S);

    // ---- Catmull-Rom interpolation for this lane's two q values ----
    const float t0 = fmaf(A, x0, C);
    const float t1 = fmaf(A, x1, C);
    float msum = 0.f;
#pragma unroll
    for (int r = 0; r < 2; ++r) {
        const float t = r ? t1 : t0;
        float u = (t - Tlo) * invh;           // in [0, 61] by construction
        u = fminf(fmaxf(u, 0.0f), 61.0f);     // safety clamp
        int c = (int)u;                        // cell index
        c = (c > 60) ? 60 : c;
        const float f = u - (float)c;          // in [0, 1]
        // CR nodes: tab[c..c+3] (cell spans points c+1 .. c+2)
        const float* tb = &tab[wave][c];
        const float p0 = tb[0], p1 = tb[1], p2 = tb[2], p3 = tb[3];
        const float d1 = p2 - p0;
        const float c2 = 2.0f * p0 - 5.0f * p1 + 4.0f * p2 - p3;
        const float c3 = 3.0f * (p1 - p2) + (p3 - p0);
        msum += fmaf(0.5f * f, fmaf(f, fmaf(f, c3, c2), d1), p1);
    }

    // mean over the row's 128 q
#pragma unroll
    for (int off = 32; off > 0; off >>= 1)
        msum += __shfl_xor(msum, off);

    if (lane == 0)
        out[b] = fmaf(alpha, msum * (1.0f / 128.0f), beta);
}

extern "C" void kernel_launch(void* const* d_in, const int* in_sizes, int n_in,
                              void* d_out, int out_size, void* d_ws, size_t ws_size,
                              hipStream_t stream) {
    const float* x  = (const float*)d_in[0];
    const float* Wt = (const float*)d_in[1];
    const float* bt = (const float*)d_in[2];
    const float* Wq = (const float*)d_in[3];
    const float* bq = (const float*)d_in[4];
    const float* Wk = (const float*)d_in[5];
    const float* bk = (const float*)d_in[6];  // cancels in softmax; unused
    const float* Wv = (const float*)d_in[7];
    const float* bv = (const float*)d_in[8];
    const float* Wo = (const float*)d_in[9];
    const float* bo = (const float*)d_in[10];
    float* out = (float*)d_out;
    float* consts = (float*)d_ws;  // 4 floats

    const int B = in_sizes[0] / SEQ;

    precompute_consts<<<1, 64, 0, stream>>>(Wt, bt, Wq, bq, Wk, bk, Wv, bv,
                                            Wo, bo, consts);

    const int grid = (B + WAVES_PER_BLOCK - 1) / WAVES_PER_BLOCK;
    attn_rowmean_kernel<<<grid, 256, 0, stream>>>(x, consts, out, B);
}